// Round 1
// 351.207 us; speedup vs baseline: 1.1321x; 1.1321x over previous
//
#include <hip/hip_runtime.h>
#include <cstdint>

// Problem: y[16384,2048] = x[16384,2048](f32) @ W[2048,2048](int8-valued, [in,out]) * scale[1,2048]
// NOTE: harness materializes integer inputs as int32 -> read weight as const int*.
// Strategy: x -> f16 (RNE; 60x error margin), W -> f16 exact, single-pass f16 MFMA GEMM.
// THIS ROUND: replace m97 128x128 structure (747 TF, MfmaUtil 33%, 1.7e7 bank conflicts)
// with the 256x256 8-phase template (T2 XOR-swizzle + T3/T4 counted vmcnt(6) + T5 setprio).

#define M_TOK 16384
#define K_DIM 2048
#define N_DIM 2048

typedef _Float16 f16;
typedef f16 f16x4 __attribute__((ext_vector_type(4)));
typedef f16 f16x8 __attribute__((ext_vector_type(8)));
typedef float f32x4 __attribute__((ext_vector_type(4)));

// ---------------------------------------------------------------------------
// Pre-pass 1: x fp32 -> f16 (RNE). Memory-bound: 134MB read + 67MB write.
// ---------------------------------------------------------------------------
__global__ void convert_x_kernel(const float* __restrict__ x, f16* __restrict__ xh) {
  const int n4 = (M_TOK * K_DIM) / 4;
  const int stride = gridDim.x * blockDim.x;
  for (int i = blockIdx.x * blockDim.x + threadIdx.x; i < n4; i += stride) {
    float4 v = ((const float4*)x)[i];
    f16x4 h;
    h[0] = (f16)v.x; h[1] = (f16)v.y; h[2] = (f16)v.z; h[3] = (f16)v.w;
    ((f16x4*)xh)[i] = h;
  }
}

// ---------------------------------------------------------------------------
// Pre-pass 2: W int32 [K][N] -> W^T f16 [N][K] (tiled transpose; |w|<=128 exact in f16)
// ---------------------------------------------------------------------------
__global__ void convert_w_kernel(const int* __restrict__ w, f16* __restrict__ wt) {
  __shared__ f16 tile[64][68];             // [n_local][k_local], padded
  const int tid = threadIdx.x;
  const int nb = blockIdx.x * 64;
  const int kb = blockIdx.y * 64;
  const int cq = tid & 15;                 // 4-wide column group
  const int rr = tid >> 4;                 // 0..15

#pragma unroll
  for (int g = 0; g < 4; ++g) {
    int krow = g * 16 + rr;
    const int* p = w + (size_t)(kb + krow) * N_DIM + nb + cq * 4;
    int4 v = *(const int4*)p;              // 4 int32 weights, coalesced along n
    tile[cq * 4 + 0][krow] = (f16)(float)v.x;
    tile[cq * 4 + 1][krow] = (f16)(float)v.y;
    tile[cq * 4 + 2][krow] = (f16)(float)v.z;
    tile[cq * 4 + 3][krow] = (f16)(float)v.w;
  }
  __syncthreads();
#pragma unroll
  for (int g = 0; g < 4; ++g) {
    int nrow = g * 16 + rr;
    f16x4 o;
#pragma unroll
    for (int j = 0; j < 4; ++j)
      o[j] = tile[nrow][cq * 4 + j];
    *(f16x4*)(wt + (size_t)(nb + nrow) * K_DIM + kb + cq * 4) = o;  // coalesced along k
  }
}

// ---------------------------------------------------------------------------
// Main GEMM: 256x256 tile, BK=64, 8 waves (2Mx4N), 8-phase counted-vmcnt schedule.
//
// LDS regions per buffer (each 128 rows x 64 k = 16KB, = one staged half-tile):
//   [0] A-R0: m rows with (m&64)==0   -> ds_read only in phase 1 (per tile)
//   [1] A-R1: m rows with (m&64)==64  -> phase 3
//   [2] B-S0: n rows with (n&32)==0   -> phase 1
//   [3] B-S1: n rows with (n&32)==32  -> phase 2
// Stage of tile t+2's region R issued exactly one phase after R's last read of
// tile t -> async DMA can land any time without racing reads. vmcnt(6) at
// phases 4/8 leaves 3 half-tiles in flight (T4: never drain to 0 in-loop).
//
// Swizzle (T2): logical k-slot s (8 f16) stored at phys slot s ^ (row&7).
// Applied on gload_lds *source* address (dest linear) and on ds_read address.
// ---------------------------------------------------------------------------
__device__ __forceinline__ void async_load16(const void* g, void* l) {
  __builtin_amdgcn_global_load_lds((__attribute__((address_space(1))) void*)g,
                                   (__attribute__((address_space(3))) void*)l,
                                   16, 0, 0);
}

#define FENCE() asm volatile("" ::: "memory")
#define BAR()   do { FENCE(); __builtin_amdgcn_s_barrier(); FENCE(); } while (0)
#define LGKM0() asm volatile("s_waitcnt lgkmcnt(0)" ::: "memory")
#define VMCNT_6() asm volatile("s_waitcnt vmcnt(6)" ::: "memory")
#define VMCNT_0() asm volatile("s_waitcnt vmcnt(0)" ::: "memory")

__global__ __launch_bounds__(512, 2) void gemm_8ph(
    const f16* __restrict__ xh, const f16* __restrict__ wt,
    const float* __restrict__ scale, float* __restrict__ out) {
  __shared__ __align__(16) f16 sm[2][4][128 * 64];   // 128 KiB

  const int tid  = threadIdx.x;
  const int wid  = tid >> 6;
  const int lane = tid & 63;
  const int wr = wid >> 2;        // wave m index (0..1), owns 128 rows
  const int wc = wid & 3;         // wave n index (0..3), owns 64 cols
  const int fr = lane & 15;
  const int kq = lane >> 4;       // 0..3

  // XCD-aware swizzle: 512 blocks % 8 == 0 -> bijective chunked map, n-fastest
  const int bid = blockIdx.x;
  const int swz = (bid & 7) * 64 + (bid >> 3);
  const int n0 = (swz & 7) * 256;
  const int m0 = (swz >> 3) * 256;

  // ---- staging geometry: wave fills chunks {2w,2w+1} (1KB each) per region ----
  const int l8   = lane >> 3;               // row within chunk
  const int slot = (lane & 7) ^ l8;         // inverse-swizzled source k-slot
  const int c0   = wid * 2;
  const int row0 = c0 * 8 + l8;             // region-linear rows for chunk 0/1
  const int row1 = row0 + 8;

  // A region row r -> global m = m0 + (r>>6)*128 + mh*64 + (r&63)
  const f16* gA0 = xh + (size_t)(m0 + (row0 >> 6) * 128 + (row0 & 63)) * K_DIM + slot * 8;
  const f16* gA1 = xh + (size_t)(m0 + (row1 >> 6) * 128 + (row1 & 63)) * K_DIM + slot * 8;
  // B region row r -> global n = n0 + (r>>5)*64 + nh*32 + (r&31)
  const f16* gB0 = wt + (size_t)(n0 + (row0 >> 5) * 64 + (row0 & 31)) * K_DIM + slot * 8;
  const f16* gB1 = wt + (size_t)(n0 + (row1 >> 5) * 64 + (row1 & 31)) * K_DIM + slot * 8;

#define STAGE_A(buf, mh, koff) do { \
    async_load16(gA0 + (mh) * 64 * K_DIM + (koff), &sm[buf][mh][c0 * 512]); \
    async_load16(gA1 + (mh) * 64 * K_DIM + (koff), &sm[buf][mh][c0 * 512 + 512]); \
  } while (0)
#define STAGE_B(buf, nh, koff) do { \
    async_load16(gB0 + (nh) * 32 * K_DIM + (koff), &sm[buf][2 + (nh)][c0 * 512]); \
    async_load16(gB1 + (nh) * 32 * K_DIM + (koff), &sm[buf][2 + (nh)][c0 * 512 + 512]); \
  } while (0)

  // ---- fragment reads: addr = row*64 + ((ks*32 + kq*8) ^ ((row&7)*8)); row&7 == fr&7
  const int kx0 = (kq * 8) ^ ((fr & 7) * 8);
  const int kx1 = (32 + kq * 8) ^ ((fr & 7) * 8);

  f16x8 a[4][2];        // current A m-half: [mi'][ks]
  f16x8 b[2][2][2];     // [nh][ni'][ks], persists across the tile's 4 phases
  f32x4 acc[8][4] = {};

#define LDA(buf, mh) do { \
    const f16* base_ = &sm[buf][mh][(wr * 64 + fr) * 64]; \
    _Pragma("unroll") for (int mi_ = 0; mi_ < 4; ++mi_) { \
      a[mi_][0] = *(const f16x8*)(base_ + mi_ * 1024 + kx0); \
      a[mi_][1] = *(const f16x8*)(base_ + mi_ * 1024 + kx1); \
    } } while (0)
#define LDB(buf, nh) do { \
    const f16* base_ = &sm[buf][2 + (nh)][(wc * 32 + fr) * 64]; \
    _Pragma("unroll") for (int ni_ = 0; ni_ < 2; ++ni_) { \
      b[nh][ni_][0] = *(const f16x8*)(base_ + ni_ * 1024 + kx0); \
      b[nh][ni_][1] = *(const f16x8*)(base_ + ni_ * 1024 + kx1); \
    } } while (0)
#define MMA(mh, nh) do { \
    __builtin_amdgcn_s_setprio(1); \
    _Pragma("unroll") for (int mi_ = 0; mi_ < 4; ++mi_) \
    _Pragma("unroll") for (int ni_ = 0; ni_ < 2; ++ni_) { \
      acc[(mh)*4+mi_][(nh)*2+ni_] = __builtin_amdgcn_mfma_f32_16x16x32_f16( \
          a[mi_][0], b[nh][ni_][0], acc[(mh)*4+mi_][(nh)*2+ni_], 0, 0, 0); \
      acc[(mh)*4+mi_][(nh)*2+ni_] = __builtin_amdgcn_mfma_f32_16x16x32_f16( \
          a[mi_][1], b[nh][ni_][1], acc[(mh)*4+mi_][(nh)*2+ni_], 0, 0, 0); \
    } \
    __builtin_amdgcn_s_setprio(0); } while (0)

  // ---- prologue: tile0 fully + tile1's first 3 half-tiles; vmcnt(6) lands tile0
  STAGE_A(0, 0, 0); STAGE_B(0, 0, 0); STAGE_B(0, 1, 0); STAGE_A(0, 1, 0);
  STAGE_A(1, 0, 64); STAGE_B(1, 0, 64); STAGE_B(1, 1, 64);
  VMCNT_6();
  BAR();

  // ---- main loop: iter i computes tiles 2i (buf0), 2i+1 (buf1); stages 2i+2, 2i+3
#pragma unroll 1
  for (int i = 0; i < 15; ++i) {
    const int k0 = i * 128;
    // ph1: tile2i q(0,0); stage tile2i+1 A-R1 (buf1[1] last read prev ph7)
    LDA(0, 0); LDB(0, 0); STAGE_A(1, 1, k0 + 64);
    BAR(); LGKM0(); MMA(0, 0); BAR();
    // ph2: q(0,1); stage tile2i+2 A-R0 (buf0[0] last read ph1)
    LDB(0, 1); STAGE_A(0, 0, k0 + 128);
    BAR(); LGKM0(); MMA(0, 1); BAR();
    // ph3: q(1,0) (B-S0 from regs); stage tile2i+2 B-S0 (read ph1)
    LDA(0, 1); STAGE_B(0, 0, k0 + 128);
    BAR(); LGKM0(); MMA(1, 0); BAR();
    // ph4: q(1,1) all-regs; stage tile2i+2 B-S1 (read ph2); land tile2i+1
    STAGE_B(0, 1, k0 + 128);
    BAR(); MMA(1, 1); VMCNT_6(); BAR();
    // ph5: tile2i+1 q(0,0); stage tile2i+2 A-R1 (buf0[1] read ph3)
    LDA(1, 0); LDB(1, 0); STAGE_A(0, 1, k0 + 128);
    BAR(); LGKM0(); MMA(0, 0); BAR();
    // ph6: stage tile2i+3 A-R0 (buf1[0] read ph5)
    LDB(1, 1); STAGE_A(1, 0, k0 + 192);
    BAR(); LGKM0(); MMA(0, 1); BAR();
    // ph7: stage tile2i+3 B-S0 (read ph5)
    LDA(1, 1); STAGE_B(1, 0, k0 + 192);
    BAR(); LGKM0(); MMA(1, 0); BAR();
    // ph8: stage tile2i+3 B-S1 (read ph6); land tile2i+2
    STAGE_B(1, 1, k0 + 192);
    BAR(); MMA(1, 1); VMCNT_6(); BAR();
  }

  // ---- tail: tiles 30 (buf0) and 31 (buf1); drain
  {
    const int k0 = 15 * 128;
    LDA(0, 0); LDB(0, 0); STAGE_A(1, 1, k0 + 64);   // tile31's last half-tile
    BAR(); LGKM0(); MMA(0, 0); BAR();
    LDB(0, 1);
    BAR(); LGKM0(); MMA(0, 1); BAR();
    LDA(0, 1);
    BAR(); LGKM0(); MMA(1, 0); BAR();
    BAR(); MMA(1, 1); VMCNT_0(); BAR();             // tile31 fully landed
    LDA(1, 0); LDB(1, 0);
    BAR(); LGKM0(); MMA(0, 0); BAR();
    LDB(1, 1);
    BAR(); LGKM0(); MMA(0, 1); BAR();
    LDA(1, 1);
    BAR(); LGKM0(); MMA(1, 0); BAR();
    MMA(1, 1);
  }

  // ---- epilogue: C/D layout col=lane&15, row=(lane>>4)*4+reg; apply scale[n]
#pragma unroll
  for (int ni = 0; ni < 4; ++ni) {
    const int col = n0 + wc * 64 + (ni >> 1) * 32 + (ni & 1) * 16 + fr;
    const float s = scale[col];
#pragma unroll
    for (int mi = 0; mi < 8; ++mi) {
      const int rbase = m0 + wr * 128 + (mi >> 2) * 64 + (mi & 3) * 16 + kq * 4;
      f32x4 v = acc[mi][ni];
#pragma unroll
      for (int r = 0; r < 4; ++r)
        out[(size_t)(rbase + r) * N_DIM + col] = v[r] * s;
    }
  }
#undef STAGE_A
#undef STAGE_B
#undef LDA
#undef LDB
#undef MMA
}

// ---------------------------------------------------------------------------
extern "C" void kernel_launch(void* const* d_in, const int* in_sizes, int n_in,
                              void* d_out, int out_size, void* d_ws, size_t ws_size,
                              hipStream_t stream) {
  const float* x     = (const float*)d_in[0];
  const float* scale = (const float*)d_in[1];
  const int* w       = (const int*)d_in[2];   // integer inputs arrive as int32
  float* out         = (float*)d_out;

  // workspace layout: x_h f16 (64MB) | W^T f16 (8MB) = 72MB
  char* ws = (char*)d_ws;
  f16* xh = (f16*)ws;
  f16* wt = (f16*)(ws + (size_t)M_TOK * K_DIM * 2);

  convert_x_kernel<<<8192, 256, 0, stream>>>(x, xh);
  convert_w_kernel<<<dim3(N_DIM / 64, K_DIM / 64), 256, 0, stream>>>(w, wt);
  gemm_8ph<<<dim3((N_DIM / 256) * (M_TOK / 256)), 512, 0, stream>>>(xh, wt, scale, out);
}